// Round 1
// baseline (906.541 us; speedup 1.0000x reference)
//
#include <hip/hip_runtime.h>
#include <math.h>

#define T_TOW 4
#define F_DIM 32
#define H_DIM 128

// ---------------- K1: bond/edge-encoder table + avg_log ----------------
__global__ void k_setup(const float* __restrict__ emb, const float* __restrict__ edge_w,
                        const float* __restrict__ edge_b, const float* __restrict__ pre_w0,
                        const float* __restrict__ pre_b0, const int* __restrict__ deg_hist,
                        float* __restrict__ ctab, float* __restrict__ scal) {
    __shared__ float e_sh[5 * 32];
    int tid = threadIdx.x;
    for (int i = tid; i < 5 * 32; i += blockDim.x) {
        int b = i >> 5, f = i & 31;
        float acc = edge_b[f];
        const float* er = emb + b * 128;
        const float* wr = edge_w + f * 128;
        for (int k = 0; k < 128; ++k) acc += er[k] * wr[k];
        e_sh[i] = acc;
    }
    __syncthreads();
    // ctab[b][c] = pre_b0[c] + sum_f pre_w0[c][64+f] * e[b][f]   (c = t*32+g)
    for (int i = tid; i < 5 * 128; i += blockDim.x) {
        int b = i >> 7, c = i & 127;
        float acc = pre_b0[c];
        const float* w = pre_w0 + c * 96 + 64;
        const float* e = e_sh + b * 32;
        for (int f = 0; f < 32; ++f) acc += w[f] * e[f];
        ctab[i] = acc;
    }
    if (tid == 0) {
        float num = 0.f, den = 0.f;
        for (int i = 0; i < 17; ++i) {
            float d = (float)deg_hist[i];
            num += logf((float)(i + 1)) * d;
            den += d;
        }
        scal[0] = num / den;   // avg_log
    }
}

// ---------------- K1b: weight transposes (for contiguous uniform s_load streams) ----
__global__ void k_transpose(const float* __restrict__ post_w0, const float* __restrict__ post_w1,
                            const float* __restrict__ lin_w,
                            float* __restrict__ w0t, float* __restrict__ w1t,
                            float* __restrict__ lwt) {
    int i = blockIdx.x * blockDim.x + threadIdx.x;
    if (i < T_TOW * F_DIM * 512) {   // post_w0 [t][g][512] -> w0t [t][512][g]
        int t = i / (F_DIM * 512);
        int r = i - t * (F_DIM * 512);
        int g = r / 512;
        int k = r - g * 512;
        w0t[(t * 512 + k) * F_DIM + g] = post_w0[i];
    }
    if (i < T_TOW * F_DIM * F_DIM) { // post_w1 [t][g][32] -> w1t [t][32][g]
        int t = i / (F_DIM * F_DIM);
        int r = i - t * (F_DIM * F_DIM);
        int g = r / F_DIM;
        int f = r - g * F_DIM;
        w1t[(t * F_DIM + f) * F_DIM + g] = post_w1[i];
    }
    if (i < H_DIM * H_DIM) {         // lin_w [j][k] -> lwt [k][j]
        int j = i >> 7, k = i & 127;
        lwt[k * H_DIM + j] = lin_w[i];
    }
}

// ---------------- K2: in-degree count ----------------
__global__ void k_count(const int* __restrict__ dst, int* __restrict__ cnt, int E) {
    int e = blockIdx.x * blockDim.x + threadIdx.x;
    if (e < E) atomicAdd(&cnt[dst[e]], 1);
}

// ---------------- K3: hierarchical exclusive scan (cnt -> row_start) -------
__global__ void k_blocksum(const int* __restrict__ cnt, int* __restrict__ bsum, int n) {
    __shared__ int sh[256];
    int i = blockIdx.x * 256 + threadIdx.x;
    sh[threadIdx.x] = (i < n) ? cnt[i] : 0;
    __syncthreads();
    for (int off = 128; off > 0; off >>= 1) {
        if (threadIdx.x < off) sh[threadIdx.x] += sh[threadIdx.x + off];
        __syncthreads();
    }
    if (threadIdx.x == 0) bsum[blockIdx.x] = sh[0];
}

__global__ void k_scanb(const int* __restrict__ bsum, int* __restrict__ boff, int nb,
                        int* __restrict__ rs, int n_nodes) {
    __shared__ int sh[512];
    int tid = threadIdx.x;
    int v = (tid < nb) ? bsum[tid] : 0;
    sh[tid] = v;
    __syncthreads();
    for (int off = 1; off < 512; off <<= 1) {
        int u = (tid >= off) ? sh[tid - off] : 0;
        __syncthreads();
        sh[tid] += u;
        __syncthreads();
    }
    if (tid < nb) boff[tid] = sh[tid] - v;       // exclusive block offsets
    if (tid == 511) rs[n_nodes] = sh[511];       // total == E
}

__global__ void k_scanc(const int* __restrict__ cnt, const int* __restrict__ boff,
                        int* __restrict__ rs, int* __restrict__ cur, int n) {
    __shared__ int sh[256];
    int i = blockIdx.x * 256 + threadIdx.x;
    int v = (i < n) ? cnt[i] : 0;
    sh[threadIdx.x] = v;
    __syncthreads();
    for (int off = 1; off < 256; off <<= 1) {
        int u = (threadIdx.x >= off) ? sh[threadIdx.x - off] : 0;
        __syncthreads();
        sh[threadIdx.x] += u;
        __syncthreads();
    }
    if (i < n) {
        int excl = sh[threadIdx.x] - v + boff[blockIdx.x];
        rs[i] = excl;
        cur[i] = excl;
    }
}

// ---------------- K4: bucket edges by dst ----------------
__global__ void k_bucket(const int* __restrict__ src, const int* __restrict__ dst,
                         const int* __restrict__ bond, int* __restrict__ cur,
                         int* __restrict__ srcS, int* __restrict__ bndS, int E) {
    int e = blockIdx.x * blockDim.x + threadIdx.x;
    if (e < E) {
        int d = dst[e];
        int slot = atomicAdd(&cur[d], 1);
        srcS[slot] = src[e];
        bndS[slot] = bond[e];
    }
}

// ---------------- K5: per-node A = W_dst@x, B = W_src@x ----------------
__global__ void k_ab(const float* __restrict__ x, const float* __restrict__ pre_w0,
                     float* __restrict__ A, float* __restrict__ B, int n) {
    long long idx = (long long)blockIdx.x * blockDim.x + threadIdx.x;
    if (idx >= (long long)n * 128) return;
    int node = (int)(idx >> 7);
    int c = (int)(idx & 127);
    const float* xr = x + (size_t)node * 128 + (c & ~31);   // tower base t*32
    const float* wr = pre_w0 + c * 96;
    float a = 0.f, b = 0.f;
#pragma unroll
    for (int f = 0; f < 32; ++f) {
        float xv = xr[f];
        a += wr[f] * xv;
        b += wr[32 + f] * xv;
    }
    A[idx] = a;
    B[idx] = b;
}

// ---------------- K6: per-node edge aggregation (1 wave / node) ------------
__global__ __launch_bounds__(64) void k_edge(
    const float* __restrict__ A, const float* __restrict__ B,
    const float* __restrict__ ctab, const float* __restrict__ pre_w1,
    const float* __restrict__ pre_b1, const int* __restrict__ rs,
    const int* __restrict__ srcS, const int* __restrict__ bndS,
    float* __restrict__ stats, int n) {
    int node = blockIdx.x;
    if (node >= n) return;
    int lane = threadIdx.x;
    int c0 = lane * 2;
    int t = c0 >> 5;
    __shared__ float cbuf[5 * 128];
    __shared__ float h0buf[128];
    for (int i = lane; i < 5 * 128; i += 64) cbuf[i] = ctab[i];

    // persistent per-lane pre_w1 rows (channels c0, c0+1)
    float w1a[32], w1b[32];
    const float* wb = pre_w1 + c0 * 32;
#pragma unroll
    for (int f = 0; f < 32; ++f) {
        w1a[f] = wb[f];
        w1b[f] = wb[32 + f];
    }
    float b1a = pre_b1[c0], b1b = pre_b1[c0 + 1];
    float2 av = ((const float2*)(A + (size_t)node * H_DIM))[lane];

    int e0 = rs[node], e1 = rs[node + 1];
    float sum0 = 0.f, sum1 = 0.f, sq0 = 0.f, sq1 = 0.f;
    float mn0 = INFINITY, mn1 = INFINITY, mx0 = -INFINITY, mx1 = -INFINITY;

    for (int e = e0; e < e1; ++e) {
        int sv = srcS[e];
        int bv = bndS[e];
        float2 b2 = ((const float2*)(B + (size_t)sv * H_DIM))[lane];
        float p0 = fmaxf(av.x + b2.x + cbuf[bv * 128 + c0], 0.f);
        float p1 = fmaxf(av.y + b2.y + cbuf[bv * 128 + c0 + 1], 0.f);
        ((float2*)h0buf)[lane] = make_float2(p0, p1);
        float hx = b1a, hy = b1b;
        const float4* h4 = (const float4*)(h0buf + t * 32);
#pragma unroll
        for (int j = 0; j < 8; ++j) {
            float4 v = h4[j];
            hx += w1a[4 * j + 0] * v.x + w1a[4 * j + 1] * v.y + w1a[4 * j + 2] * v.z + w1a[4 * j + 3] * v.w;
            hy += w1b[4 * j + 0] * v.x + w1b[4 * j + 1] * v.y + w1b[4 * j + 2] * v.z + w1b[4 * j + 3] * v.w;
        }
        sum0 += hx; sum1 += hy;
        sq0 += hx * hx; sq1 += hy * hy;
        mn0 = fminf(mn0, hx); mn1 = fminf(mn1, hy);
        mx0 = fmaxf(mx0, hx); mx1 = fmaxf(mx1, hy);
    }
    if (e1 <= e0) { mn0 = mn1 = mx0 = mx1 = 0.f; }   // `has` mask
    float2* st2 = (float2*)(stats + (size_t)node * 512);
    st2[lane]        = make_float2(sum0, sum1);
    st2[64 + lane]   = make_float2(sq0, sq1);
    st2[128 + lane]  = make_float2(mn0, mn1);
    st2[192 + lane]  = make_float2(mx0, mx1);
}

// ---------------- K7: post-MLP, node-per-lane, tower-per-wave --------------
__global__ __launch_bounds__(256) void k_post(
    const float* __restrict__ x, const float* __restrict__ stats,
    const int* __restrict__ rs, const float* __restrict__ scal,
    const float* __restrict__ w0t, const float* __restrict__ w1t,
    const float* __restrict__ post_b0, const float* __restrict__ post_b1,
    float* __restrict__ y1, int n) {
    int lane = threadIdx.x & 63;
    int t = threadIdx.x >> 6;           // tower
    int node = blockIdx.x * 64 + lane;
    if (node >= n) return;
    int cnt = rs[node + 1] - rs[node];
    float cnt1 = fmaxf((float)cnt, 1.f);
    float inv = 1.f / cnt1;
    float logd = logf(cnt1 + 1.f);
    float avg = scal[0];
    float s1 = logd / avg, s2 = avg / logd;

    float acc[32];
    const float* b0 = post_b0 + t * 32;
#pragma unroll
    for (int g = 0; g < 32; ++g) acc[g] = b0[g];

    const float* xr = x + (size_t)node * 128 + t * 32;
    const float* wt = w0t + t * 512 * 32;
    // x part (cols 0..31)
    for (int f = 0; f < 32; ++f) {
        float v = xr[f];
        const float* wc = wt + f * 32;
#pragma unroll
        for (int g = 0; g < 32; ++g) acc[g] += wc[g] * v;
    }
    const float* st = stats + (size_t)node * 512 + t * 32;
    // agg sub-blocks: s, mean, mn, mx, std ; scaled copies folded in (x1, x s1, x s2)
#pragma unroll
    for (int sub = 0; sub < 5; ++sub) {
        for (int f = 0; f < 32; ++f) {
            float v;
            if (sub == 0) v = st[f];
            else if (sub == 1) v = st[f] * inv;
            else if (sub == 2) v = st[256 + f];
            else if (sub == 3) v = st[384 + f];
            else {
                float sm = st[f] * inv;
                float q = st[128 + f] * inv;
                v = sqrtf(fmaxf(q - sm * sm, 0.f) + 1e-5f);
            }
            float v1 = v * s1, v2 = v * s2;
            const float* wc0 = wt + (32 + 0 * 160 + sub * 32 + f) * 32;
            const float* wc1 = wt + (32 + 1 * 160 + sub * 32 + f) * 32;
            const float* wc2 = wt + (32 + 2 * 160 + sub * 32 + f) * 32;
#pragma unroll
            for (int g = 0; g < 32; ++g) acc[g] += wc0[g] * v + wc1[g] * v1 + wc2[g] * v2;
        }
    }
    // ReLU + post_w1
    float r[32];
#pragma unroll
    for (int g = 0; g < 32; ++g) r[g] = fmaxf(acc[g], 0.f);
    const float* b1 = post_b1 + t * 32;
#pragma unroll
    for (int g = 0; g < 32; ++g) acc[g] = b1[g];
    const float* w1 = w1t + t * 32 * 32;
#pragma unroll
    for (int f = 0; f < 32; ++f) {
        float v = r[f];
        const float* wc = w1 + f * 32;
#pragma unroll
        for (int g = 0; g < 32; ++g) acc[g] += wc[g] * v;
    }
    float* yr = y1 + (size_t)node * 128 + t * 32;
#pragma unroll
    for (int g = 0; g < 32; ++g) yr[g] = acc[g];
}

// ---------------- K8: Linear(128,128) + LayerNorm + ReLU + residual --------
__global__ __launch_bounds__(64) void k_final(
    const float* __restrict__ y1, const float* __restrict__ lwt,
    const float* __restrict__ lin_b, const float* __restrict__ ln_g,
    const float* __restrict__ ln_b, const float* __restrict__ x,
    float* __restrict__ out, int n) {
    int node = blockIdx.x * 64 + threadIdx.x;
    if (node >= n) return;
    float acc[128];
#pragma unroll
    for (int j = 0; j < 128; ++j) acc[j] = lin_b[j];
    const float* yr = y1 + (size_t)node * 128;
    for (int k = 0; k < 128; ++k) {
        float v = yr[k];
        const float* wr = lwt + k * 128;
#pragma unroll
        for (int j = 0; j < 128; ++j) acc[j] += wr[j] * v;
    }
    float mu = 0.f;
#pragma unroll
    for (int j = 0; j < 128; ++j) mu += acc[j];
    mu *= (1.f / 128.f);
    float var = 0.f;
#pragma unroll
    for (int j = 0; j < 128; ++j) {
        float d = acc[j] - mu;
        var += d * d;
    }
    var *= (1.f / 128.f);
    float rstd = rsqrtf(var + 1e-5f);
    const float* xr = x + (size_t)node * 128;
    float* orow = out + (size_t)node * 128;
#pragma unroll
    for (int j = 0; j < 128; ++j) {
        float o = (acc[j] - mu) * rstd * ln_g[j] + ln_b[j];
        o = fmaxf(o, 0.f);
        orow[j] = xr[j] + o;
    }
}

extern "C" void kernel_launch(void* const* d_in, const int* in_sizes, int n_in,
                              void* d_out, int out_size, void* d_ws, size_t ws_size,
                              hipStream_t stream) {
    const float* atom_x   = (const float*)d_in[0];
    const int*   bond_x   = (const int*)d_in[1];
    const int*   aei      = (const int*)d_in[2];
    const int*   deg_hist = (const int*)d_in[3];
    const float* emb      = (const float*)d_in[4];
    const float* edge_w   = (const float*)d_in[5];
    const float* edge_b   = (const float*)d_in[6];
    const float* pre_w0   = (const float*)d_in[7];
    // d_in[8] = pre_b0
    const float* pre_b0   = (const float*)d_in[8];
    const float* pre_w1   = (const float*)d_in[9];
    const float* pre_b1   = (const float*)d_in[10];
    const float* post_w0  = (const float*)d_in[11];
    const float* post_b0  = (const float*)d_in[12];
    const float* post_w1  = (const float*)d_in[13];
    const float* post_b1  = (const float*)d_in[14];
    const float* lin_w    = (const float*)d_in[15];
    const float* lin_b    = (const float*)d_in[16];
    const float* ln_g     = (const float*)d_in[17];
    const float* ln_b     = (const float*)d_in[18];

    int n = in_sizes[0] / H_DIM;     // 40000
    int E = in_sizes[1];             // 320000
    const int* src = aei;
    const int* dst = aei + E;

    char* ws = (char*)d_ws;
    size_t off = 0;
    auto alloc = [&](size_t bytes) {
        size_t r = off;
        off = (off + bytes + 511) & ~(size_t)511;
        return r;
    };
    float* ctab  = (float*)(ws + alloc(5 * 128 * 4));
    float* scal  = (float*)(ws + alloc(256));
    float* w0t   = (float*)(ws + alloc((size_t)4 * 512 * 32 * 4));
    float* w1t   = (float*)(ws + alloc(4 * 32 * 32 * 4));
    float* lwt   = (float*)(ws + alloc(128 * 128 * 4));
    int*   cnt   = (int*)(ws + alloc((size_t)n * 4));
    int*   rs    = (int*)(ws + alloc((size_t)(n + 1) * 4));
    int*   cur   = (int*)(ws + alloc((size_t)n * 4));
    int*   bsum  = (int*)(ws + alloc(4096));
    int*   boff  = (int*)(ws + alloc(4096));
    int*   srcS  = (int*)(ws + alloc((size_t)E * 4));
    int*   bndS  = (int*)(ws + alloc((size_t)E * 4));
    float* A     = (float*)(ws + alloc((size_t)n * 128 * 4));
    float* B     = (float*)(ws + alloc((size_t)n * 128 * 4));
    float* stats = (float*)(ws + alloc((size_t)n * 512 * 4));
    float* y1    = A;   // A is dead after k_edge; reuse for post-MLP output

    if (off > ws_size) return;   // ws too small -> visible validation failure

    hipMemsetAsync(cnt, 0, (size_t)n * 4, stream);
    k_setup<<<1, 256, 0, stream>>>(emb, edge_w, edge_b, pre_w0, pre_b0, deg_hist, ctab, scal);
    k_transpose<<<(T_TOW * F_DIM * 512 + 255) / 256, 256, 0, stream>>>(post_w0, post_w1, lin_w,
                                                                       w0t, w1t, lwt);
    k_count<<<(E + 255) / 256, 256, 0, stream>>>(dst, cnt, E);
    int nb = (n + 255) / 256;
    k_blocksum<<<nb, 256, 0, stream>>>(cnt, bsum, n);
    k_scanb<<<1, 512, 0, stream>>>(bsum, boff, nb, rs, n);
    k_scanc<<<nb, 256, 0, stream>>>(cnt, boff, rs, cur, n);
    k_bucket<<<(E + 255) / 256, 256, 0, stream>>>(src, dst, bond_x, cur, srcS, bndS, E);
    k_ab<<<(int)(((long long)n * 128 + 255) / 256), 256, 0, stream>>>(atom_x, pre_w0, A, B, n);
    k_edge<<<n, 64, 0, stream>>>(A, B, ctab, pre_w1, pre_b1, rs, srcS, bndS, stats, n);
    k_post<<<(n + 63) / 64, 256, 0, stream>>>(atom_x, stats, rs, scal, w0t, w1t,
                                              post_b0, post_b1, y1, n);
    k_final<<<(n + 63) / 64, 64, 0, stream>>>(y1, lwt, lin_b, ln_g, ln_b, atom_x,
                                              (float*)d_out, n);
}